// Round 11
// baseline (116.516 us; speedup 1.0000x reference)
//
#include <hip/hip_runtime.h>

// 2-layer GRU, B=131072, T=24, H=8. MFMA formulation (verified r8).
// Round-11: ILP x2 — each wave processes TWO independent 32-seq groups
// (64 seqs/wave, 2 waves/SIMD). The two recurrence chains interleave inside
// the wave, filling the MFMA-latency + trans-chain stalls that four
// lock-stepped waves could not (r10: 44us, VALUBusy 62% == pure issue demand,
// 38% all-waves-stalled). Manual r9 pipeline dropped (measured zero effect);
// permlane32_swap + stride-33 G1 kept.

typedef __fp16 h2f    __attribute__((ext_vector_type(2)));
typedef __fp16 half8  __attribute__((ext_vector_type(8)));
typedef float  f32x16 __attribute__((ext_vector_type(16)));

#define LOG2E 1.44269504088896f

__device__ __forceinline__ h2f pk2f(float a, float b) {
  return __builtin_amdgcn_cvt_pkrtz(a, b);
}

union H8U { half8 h; unsigned u[4]; h2f p[4]; };

// lanes<32 receive x from lane+32; lanes>=32 keep a don't-care copy
// (A-frag rows k=8..15 are zero, so B content there never contributes).
__device__ __forceinline__ unsigned from_upper(unsigned x) {
  auto r = __builtin_amdgcn_permlane32_swap((int)x, (int)x, false, false);
  return (unsigned)r[1];
}

#define MFMA_(A, B, C) __builtin_amdgcn_mfma_f32_32x32x16_f16((A), (B), (C), 0, 0, 0)

#define TOKSEL(p0, p1, p2, p3, t) \
  (((((t) < 6) ? (p0) : ((t) < 12) ? (p1) : ((t) < 18) ? (p2) : (p3)) >> (5 * ((t) % 6))) & 31u)

#define BUILD_C1(c1, gp) do { \
  (c1)[0] = (gp)[0];  (c1)[1] = (gp)[1];  (c1)[2] = (gp)[2];  (c1)[3] = (gp)[3]; \
  (c1)[4] = (gp)[8];  (c1)[5] = (gp)[9];  (c1)[6] = (gp)[10]; (c1)[7] = (gp)[11]; \
  (c1)[8] = bn1[0];  (c1)[9] = bn1[1];  (c1)[10] = bn1[2]; (c1)[11] = bn1[3]; \
  (c1)[12] = 0.f; (c1)[13] = 0.f; (c1)[14] = 0.f; (c1)[15] = 0.f; \
} while (0)

#define L1_CELL(d1, gp, h1v, f1) do { \
  _Pragma("unroll") \
  for (int i = 0; i < 4; ++i) { \
    const float r_ = __builtin_amdgcn_rcpf(1.f + __builtin_amdgcn_exp2f((d1)[i])); \
    const float z_ = __builtin_amdgcn_rcpf(1.f + __builtin_amdgcn_exp2f((d1)[4 + i])); \
    const float na_ = fmaf(r_, (d1)[8 + i], (gp)[16 + i]); \
    const float n_ = fmaf(-2.f, __builtin_amdgcn_rcpf(1.f + __builtin_amdgcn_exp2f(na_)), 1.f); \
    (h1v)[i] = n_ + z_ * ((h1v)[i] - n_); \
  } \
  const unsigned a_ = __builtin_bit_cast(unsigned, pk2f((h1v)[0], (h1v)[1])); \
  const unsigned b_ = __builtin_bit_cast(unsigned, pk2f((h1v)[2], (h1v)[3])); \
  (f1).u[0] = a_; (f1).u[1] = b_; \
  (f1).u[2] = from_upper(a_); (f1).u[3] = from_upper(b_); \
} while (0)

#define L2_CELL(dg, dh, h2v, f2) do { \
  _Pragma("unroll") \
  for (int i = 0; i < 4; ++i) { \
    const float r_ = __builtin_amdgcn_rcpf(1.f + __builtin_amdgcn_exp2f((dg)[i])); \
    const float z_ = __builtin_amdgcn_rcpf(1.f + __builtin_amdgcn_exp2f((dg)[4 + i])); \
    const float gin_ = (dg)[8 + i] - (dh)[8 + i] + bi2n[i]; \
    const float na_ = fmaf(r_, (dh)[8 + i], gin_); \
    const float n_ = fmaf(-2.f, __builtin_amdgcn_rcpf(1.f + __builtin_amdgcn_exp2f(na_)), 1.f); \
    (h2v)[i] = n_ + z_ * ((h2v)[i] - n_); \
  } \
  const unsigned a_ = __builtin_bit_cast(unsigned, pk2f((h2v)[0], (h2v)[1])); \
  const unsigned b_ = __builtin_bit_cast(unsigned, pk2f((h2v)[2], (h2v)[3])); \
  (f2).u[0] = a_; (f2).u[1] = b_; \
  (f2).u[2] = from_upper(a_); (f2).u[3] = from_upper(b_); \
} while (0)

__global__ __launch_bounds__(256, 2) void gru2_mfma(
    const int* __restrict__ inputs,
    const float* __restrict__ emb,
    const float* __restrict__ w_ih1, const float* __restrict__ w_hh1,
    const float* __restrict__ b_ih1, const float* __restrict__ b_hh1,
    const float* __restrict__ w_ih2, const float* __restrict__ w_hh2,
    const float* __restrict__ b_ih2, const float* __restrict__ b_hh2,
    float* __restrict__ out)
{
  __shared__ float G1f[27 * 33];   // [token][gate], odd stride: token->bank bijective
  __shared__ int   TK[256 * 25];   // 256 seqs x 24 tokens, stride 25

  const int tid   = threadIdx.x;
  const int lane  = tid & 63;
  const int wid   = tid >> 6;
  const int half_ = lane >> 5;
  const int col   = lane & 31;

  // ---- G1 table: scaled input-side gates for all 27 tokens ----
  for (int idx = tid; idx < 27 * 24; idx += 256) {
    const int tok = idx / 24, g = idx - tok * 24;
    const float s = (g < 16) ? -LOG2E : 2.f * LOG2E;
    float a = b_ih1[g] + ((g < 16) ? b_hh1[g] : 0.f);
    if (tok != 0) {
      #pragma unroll
      for (int j = 0; j < 8; ++j) a = fmaf(w_ih1[g * 8 + j], emb[tok * 8 + j], a);
    }
    G1f[tok * 33 + g] = s * a;
  }

  // ---- stage this block's 256x24 tokens, coalesced ----
  const long gbase = (long)blockIdx.x * (256 * 24);
  #pragma unroll
  for (int k = 0; k < 24; ++k) {
    const int i = tid + k * 256;
    TK[(i / 24) * 25 + (i % 24)] = inputs[gbase + i];
  }
  __syncthreads();

  // two seq groups per wave
  const int slA = wid * 64 + col;
  const int slB = slA + 32;

  unsigned pwA[4] = {0u, 0u, 0u, 0u}, pwB[4] = {0u, 0u, 0u, 0u};
  #pragma unroll
  for (int t = 0; t < 24; ++t) {
    pwA[t / 6] |= ((unsigned)TK[slA * 25 + t]) << (5 * (t % 6));
    pwB[t / 6] |= ((unsigned)TK[slB * 25 + t]) << (5 * (t % 6));
  }
  const unsigned pA0 = pwA[0], pA1 = pwA[1], pA2 = pwA[2], pA3 = pwA[3];
  const unsigned pB0 = pwB[0], pB1 = pwB[1], pB2 = pwB[2], pB3 = pwB[3];

  // ---- weight A-frags (lane<32: row=col of W, k=0..7 scaled; else zero) ----
  auto loadW = [&](const float* w) -> half8 {
    H8U u;
    u.u[0] = u.u[1] = u.u[2] = u.u[3] = 0u;
    if (half_ == 0 && col < 24) {
      const float s = (col < 16) ? -LOG2E : 2.f * LOG2E;
      const float4* p = (const float4*)(w + col * 8);
      const float4 x = p[0], y = p[1];
      u.p[0] = pk2f(x.x * s, x.y * s);
      u.p[1] = pk2f(x.z * s, x.w * s);
      u.p[2] = pk2f(y.x * s, y.y * s);
      u.p[3] = pk2f(y.z * s, y.w * s);
    }
    return u.h;
  };
  const half8 wa1  = loadW(w_hh1);
  const half8 wa2i = loadW(w_ih2);
  const half8 wa2h = loadW(w_hh2);

  // ---- layer-2 bias C-frag ----
  f32x16 c2;
  #pragma unroll
  for (int r = 0; r < 16; ++r) {
    const int m = (r & 3) + 8 * (r >> 2) + 4 * half_;
    float v;
    if (m < 16)      v = -LOG2E * (b_ih2[m] + b_hh2[m]);
    else if (m < 24) v = 2.f * LOG2E * b_hh2[m];
    else             v = 0.f;
    c2[r] = v;
  }
  float bn1[4], bi2n[4];
  #pragma unroll
  for (int i = 0; i < 4; ++i) {
    bn1[i]  = 2.f * LOG2E * b_hh1[16 + 4 * half_ + i];
    bi2n[i] = 2.f * LOG2E * b_ih2[16 + 4 * half_ + i];
  }

  float h1vA[4] = {0.f, 0.f, 0.f, 0.f}, h2vA[4] = {0.f, 0.f, 0.f, 0.f};
  float h1vB[4] = {0.f, 0.f, 0.f, 0.f}, h2vB[4] = {0.f, 0.f, 0.f, 0.f};
  H8U f1A, f2A, f1B, f2B;
  f1A.u[0] = f1A.u[1] = f1A.u[2] = f1A.u[3] = 0u;
  f2A = f1A; f1B = f1A; f2B = f1A;

  const float* g1base = G1f + half_ * 4;

  #pragma unroll
  for (int t = 0; t < 24; ++t) {
    const unsigned tokA = TOKSEL(pA0, pA1, pA2, pA3, t);
    const unsigned tokB = TOKSEL(pB0, pB1, pB2, pB3, t);
    const float* gpA = g1base + tokA * 33;
    const float* gpB = g1base + tokB * 33;

    f32x16 c1A, c1B;
    BUILD_C1(c1A, gpA);
    BUILD_C1(c1B, gpB);

    // issue all four independent MFMAs up front; the two groups' chains
    // interleave to cover MFMA latency and trans-chain stalls
    const f32x16 dhA = MFMA_(wa2h, f2A.h, c2);
    const f32x16 dhB = MFMA_(wa2h, f2B.h, c2);
    const f32x16 d1A = MFMA_(wa1, f1A.h, c1A);
    const f32x16 d1B = MFMA_(wa1, f1B.h, c1B);

    L1_CELL(d1A, gpA, h1vA, f1A);
    L1_CELL(d1B, gpB, h1vB, f1B);

    const f32x16 dgA = MFMA_(wa2i, f1A.h, dhA);
    const f32x16 dgB = MFMA_(wa2i, f1B.h, dhB);

    L2_CELL(dgA, dhA, h2vA, f2A);
    L2_CELL(dgB, dhB, h2vB, f2B);
  }

  const long base = (long)blockIdx.x * 256;
  *(float4*)(out + (base + slA) * 8 + 4 * half_) =
      make_float4(h2vA[0], h2vA[1], h2vA[2], h2vA[3]);
  *(float4*)(out + (base + slB) * 8 + 4 * half_) =
      make_float4(h2vB[0], h2vB[1], h2vB[2], h2vB[3]);
}

extern "C" void kernel_launch(void* const* d_in, const int* in_sizes, int n_in,
                              void* d_out, int out_size, void* d_ws, size_t ws_size,
                              hipStream_t stream) {
  const int*   inputs = (const int*)d_in[0];
  const float* emb    = (const float*)d_in[1];
  const float* w_ih1  = (const float*)d_in[2];
  const float* w_hh1  = (const float*)d_in[3];
  const float* b_ih1  = (const float*)d_in[4];
  const float* b_hh1  = (const float*)d_in[5];
  const float* w_ih2  = (const float*)d_in[6];
  const float* w_hh2  = (const float*)d_in[7];
  const float* b_ih2  = (const float*)d_in[8];
  const float* b_hh2  = (const float*)d_in[9];
  float* out = (float*)d_out;

  const int B = in_sizes[0] / 24;        // 131072
  const int grid = B / 256;              // 512 blocks, 64 seqs per wave

  hipLaunchKernelGGL(gru2_mfma, dim3(grid), dim3(256), 0, stream,
                     inputs, emb, w_ih1, w_hh1, b_ih1, b_hh1,
                     w_ih2, w_hh2, b_ih2, b_hh2, out);
}

// Round 14
// 114.539 us; speedup vs baseline: 1.0173x; 1.0173x over previous
//
#include <hip/hip_runtime.h>

// 2-layer GRU, B=131072, T=24, H=8. MFMA formulation (math verified r8,
// absmax 3.9e-3). Round-12: ROLLED time loop. r10/r11 evidence: perf
// insensitive to TLP/ILP/bank-conflicts/pipelining; fully-unrolled body is
// ~29-56KB of straight-line code => I-cache streaming is the suspected 40%
// no-issue hole. Outer loop over 4 packed-token dwords (cndmask select, no
// dynamic indexing), inner unroll-6 (compile-time shifts). Body ~6KB.

typedef __fp16 h2f    __attribute__((ext_vector_type(2)));
typedef __fp16 half8  __attribute__((ext_vector_type(8)));
typedef float  f32x16 __attribute__((ext_vector_type(16)));

#define LOG2E 1.44269504088896f

__device__ __forceinline__ h2f pk2f(float a, float b) {
  return __builtin_amdgcn_cvt_pkrtz(a, b);
}

union H8U { half8 h; unsigned u[4]; h2f p[4]; };

// lanes<32 receive x from lane+32; lanes>=32 keep a don't-care copy
// (A-frag rows k=8..15 are zero, so B content there never contributes).
__device__ __forceinline__ unsigned from_upper(unsigned x) {
  auto r = __builtin_amdgcn_permlane32_swap((int)x, (int)x, false, false);
  return (unsigned)r[1];
}

#define MFMA_(A, B, C) __builtin_amdgcn_mfma_f32_32x32x16_f16((A), (B), (C), 0, 0, 0)

__global__ __launch_bounds__(256, 4) void gru2_mfma(
    const int* __restrict__ inputs,
    const float* __restrict__ emb,
    const float* __restrict__ w_ih1, const float* __restrict__ w_hh1,
    const float* __restrict__ b_ih1, const float* __restrict__ b_hh1,
    const float* __restrict__ w_ih2, const float* __restrict__ w_hh2,
    const float* __restrict__ b_ih2, const float* __restrict__ b_hh2,
    float* __restrict__ out)
{
  __shared__ float G1f[27 * 33];   // [token][gate], odd stride: token->bank bijective
  __shared__ int   TK[128 * 25];

  const int tid   = threadIdx.x;
  const int lane  = tid & 63;
  const int wid   = tid >> 6;
  const int half_ = lane >> 5;
  const int col   = lane & 31;

  // ---- G1 table: scaled input-side gates for all 27 tokens ----
  for (int idx = tid; idx < 27 * 24; idx += 256) {
    const int tok = idx / 24, g = idx - tok * 24;
    const float s = (g < 16) ? -LOG2E : 2.f * LOG2E;
    float a = b_ih1[g] + ((g < 16) ? b_hh1[g] : 0.f);
    if (tok != 0) {
      #pragma unroll
      for (int j = 0; j < 8; ++j) a = fmaf(w_ih1[g * 8 + j], emb[tok * 8 + j], a);
    }
    G1f[tok * 33 + g] = s * a;
  }

  // ---- stage this block's 128x24 tokens, coalesced ----
  const long gbase = (long)blockIdx.x * (128 * 24);
  #pragma unroll
  for (int k = 0; k < 12; ++k) {
    const int i = tid + k * 256;
    TK[(i / 24) * 25 + (i % 24)] = inputs[gbase + i];
  }
  __syncthreads();

  const int sl = wid * 32 + col;
  unsigned pkw[4] = {0u, 0u, 0u, 0u};
  #pragma unroll
  for (int t = 0; t < 24; ++t)
    pkw[t / 6] |= ((unsigned)TK[sl * 25 + t]) << (5 * (t % 6));
  const unsigned pk0 = pkw[0], pk1 = pkw[1], pk2_ = pkw[2], pk3 = pkw[3];

  // ---- weight A-frags (lane<32: row=col of W, k=0..7 scaled; else zero) ----
  auto loadW = [&](const float* w) -> half8 {
    H8U u;
    u.u[0] = u.u[1] = u.u[2] = u.u[3] = 0u;
    if (half_ == 0 && col < 24) {
      const float s = (col < 16) ? -LOG2E : 2.f * LOG2E;
      const float4* p = (const float4*)(w + col * 8);
      const float4 x = p[0], y = p[1];
      u.p[0] = pk2f(x.x * s, x.y * s);
      u.p[1] = pk2f(x.z * s, x.w * s);
      u.p[2] = pk2f(y.x * s, y.y * s);
      u.p[3] = pk2f(y.z * s, y.w * s);
    }
    return u.h;
  };
  const half8 wa1  = loadW(w_hh1);
  const half8 wa2i = loadW(w_ih2);
  const half8 wa2h = loadW(w_hh2);

  // ---- layer-2 bias C-frag ----
  f32x16 c2;
  #pragma unroll
  for (int r = 0; r < 16; ++r) {
    const int m = (r & 3) + 8 * (r >> 2) + 4 * half_;
    float v;
    if (m < 16)      v = -LOG2E * (b_ih2[m] + b_hh2[m]);
    else if (m < 24) v = 2.f * LOG2E * b_hh2[m];
    else             v = 0.f;
    c2[r] = v;
  }
  float bn1[4], bi2n[4];
  #pragma unroll
  for (int i = 0; i < 4; ++i) {
    bn1[i]  = 2.f * LOG2E * b_hh1[16 + 4 * half_ + i];
    bi2n[i] = 2.f * LOG2E * b_ih2[16 + 4 * half_ + i];
  }

  float h1v[4] = {0.f, 0.f, 0.f, 0.f}, h2v[4] = {0.f, 0.f, 0.f, 0.f};
  H8U f1, f2;
  f1.u[0] = f1.u[1] = f1.u[2] = f1.u[3] = 0u;
  f2 = f1;

  const float* g1base = G1f + half_ * 4;

  // ---- rolled time loop: 4 outer iterations x 6 unrolled steps ----
  for (int t6 = 0; t6 < 4; ++t6) {
    // select packed-token dword without dynamic indexing (cndmask chain)
    const unsigned pw = (t6 == 0) ? pk0 : (t6 == 1) ? pk1 : (t6 == 2) ? pk2_ : pk3;

    #pragma unroll
    for (int j = 0; j < 6; ++j) {
      const unsigned tok = (pw >> (5 * j)) & 31u;
      const float* gp = g1base + tok * 33;

      f32x16 c1;
      c1[0] = gp[0];  c1[1] = gp[1];  c1[2] = gp[2];  c1[3] = gp[3];
      c1[4] = gp[8];  c1[5] = gp[9];  c1[6] = gp[10]; c1[7] = gp[11];
      c1[8] = bn1[0]; c1[9] = bn1[1]; c1[10] = bn1[2]; c1[11] = bn1[3];
      c1[12] = 0.f; c1[13] = 0.f; c1[14] = 0.f; c1[15] = 0.f;

      const f32x16 dh = MFMA_(wa2h, f2.h, c2);     // L2 recurrent (independent)
      const f32x16 d1 = MFMA_(wa1, f1.h, c1);      // L1 full gates

      #pragma unroll
      for (int i = 0; i < 4; ++i) {
        const float r = __builtin_amdgcn_rcpf(1.f + __builtin_amdgcn_exp2f(d1[i]));
        const float z = __builtin_amdgcn_rcpf(1.f + __builtin_amdgcn_exp2f(d1[4 + i]));
        const float na = fmaf(r, d1[8 + i], gp[16 + i]);
        const float n = fmaf(-2.f, __builtin_amdgcn_rcpf(1.f + __builtin_amdgcn_exp2f(na)), 1.f);
        h1v[i] = n + z * (h1v[i] - n);
      }
      {
        const unsigned a = __builtin_bit_cast(unsigned, pk2f(h1v[0], h1v[1]));
        const unsigned b = __builtin_bit_cast(unsigned, pk2f(h1v[2], h1v[3]));
        f1.u[0] = a; f1.u[1] = b;
        f1.u[2] = from_upper(a); f1.u[3] = from_upper(b);
      }

      const f32x16 dg = MFMA_(wa2i, f1.h, dh);     // L2 input gates, chained C

      #pragma unroll
      for (int i = 0; i < 4; ++i) {
        const float r = __builtin_amdgcn_rcpf(1.f + __builtin_amdgcn_exp2f(dg[i]));
        const float z = __builtin_amdgcn_rcpf(1.f + __builtin_amdgcn_exp2f(dg[4 + i]));
        const float gin = dg[8 + i] - dh[8 + i] + bi2n[i];
        const float na = fmaf(r, dh[8 + i], gin);
        const float n = fmaf(-2.f, __builtin_amdgcn_rcpf(1.f + __builtin_amdgcn_exp2f(na)), 1.f);
        h2v[i] = n + z * (h2v[i] - n);
      }
      {
        const unsigned a = __builtin_bit_cast(unsigned, pk2f(h2v[0], h2v[1]));
        const unsigned b = __builtin_bit_cast(unsigned, pk2f(h2v[2], h2v[3]));
        f2.u[0] = a; f2.u[1] = b;
        f2.u[2] = from_upper(a); f2.u[3] = from_upper(b);
      }
    }
  }

  const long seq = (long)blockIdx.x * 128 + sl;
  *(float4*)(out + seq * 8 + 4 * half_) =
      make_float4(h2v[0], h2v[1], h2v[2], h2v[3]);
}

extern "C" void kernel_launch(void* const* d_in, const int* in_sizes, int n_in,
                              void* d_out, int out_size, void* d_ws, size_t ws_size,
                              hipStream_t stream) {
  const int*   inputs = (const int*)d_in[0];
  const float* emb    = (const float*)d_in[1];
  const float* w_ih1  = (const float*)d_in[2];
  const float* w_hh1  = (const float*)d_in[3];
  const float* b_ih1  = (const float*)d_in[4];
  const float* b_hh1  = (const float*)d_in[5];
  const float* w_ih2  = (const float*)d_in[6];
  const float* w_hh2  = (const float*)d_in[7];
  const float* b_ih2  = (const float*)d_in[8];
  const float* b_hh2  = (const float*)d_in[9];
  float* out = (float*)d_out;

  const int B = in_sizes[0] / 24;        // 131072
  const int grid = B / 128;              // 1024 blocks, 4 waves/SIMD

  hipLaunchKernelGGL(gru2_mfma, dim3(grid), dim3(256), 0, stream,
                     inputs, emb, w_ih1, w_hh1, b_ih1, b_hh1,
                     w_ih2, w_hh2, b_ih2, b_hh2, out);
}

// Round 16
// 112.262 us; speedup vs baseline: 1.0379x; 1.0203x over previous
//
#include <hip/hip_runtime.h>

// 2-layer GRU, B=131072, T=24, H=8. MFMA formulation (math verified r8).
// Round-15: phase-stagger + register prefetch.
// Evidence: r10/11/12-14 falsified bank-conflict / pipelining / ILP / I-cache
// theories. VALUBusy 64% == exact issue demand (48 trans*8 + ~150 VALU*2 per
// wave-step, x4 waves); the 36% hole = correlated stalls of 4 identical
// lock-stepped waves. Fix: (a) s_sleep stagger keyed to hashed blockIdx so
// co-resident waves run out of phase; (b) G1-row prefetch one step ahead in
// registers so ds_read latency is off the d1-MFMA path.

typedef __fp16 h2f    __attribute__((ext_vector_type(2)));
typedef __fp16 half8  __attribute__((ext_vector_type(8)));
typedef float  f32x16 __attribute__((ext_vector_type(16)));

#define LOG2E 1.44269504088896f

__device__ __forceinline__ h2f pk2f(float a, float b) {
  return __builtin_amdgcn_cvt_pkrtz(a, b);
}

union H8U { half8 h; unsigned u[4]; h2f p[4]; };

// lanes<32 receive x from lane+32; lanes>=32 keep a don't-care copy
// (A-frag rows k=8..15 are zero, so B content there never contributes).
__device__ __forceinline__ unsigned from_upper(unsigned x) {
  auto r = __builtin_amdgcn_permlane32_swap((int)x, (int)x, false, false);
  return (unsigned)r[1];
}

#define MFMA_(A, B, C) __builtin_amdgcn_mfma_f32_32x32x16_f16((A), (B), (C), 0, 0, 0)

__global__ __launch_bounds__(256, 4) void gru2_mfma(
    const int* __restrict__ inputs,
    const float* __restrict__ emb,
    const float* __restrict__ w_ih1, const float* __restrict__ w_hh1,
    const float* __restrict__ b_ih1, const float* __restrict__ b_hh1,
    const float* __restrict__ w_ih2, const float* __restrict__ w_hh2,
    const float* __restrict__ b_ih2, const float* __restrict__ b_hh2,
    float* __restrict__ out)
{
  __shared__ float G1f[27 * 33];   // [token][gate], odd stride: token->bank bijective
  __shared__ int   TK[128 * 25];

  const int tid   = threadIdx.x;
  const int lane  = tid & 63;
  const int wid   = tid >> 6;
  const int half_ = lane >> 5;
  const int col   = lane & 31;

  // ---- G1 table: scaled input-side gates for all 27 tokens ----
  for (int idx = tid; idx < 27 * 24; idx += 256) {
    const int tok = idx / 24, g = idx - tok * 24;
    const float s = (g < 16) ? -LOG2E : 2.f * LOG2E;
    float a = b_ih1[g] + ((g < 16) ? b_hh1[g] : 0.f);
    if (tok != 0) {
      #pragma unroll
      for (int j = 0; j < 8; ++j) a = fmaf(w_ih1[g * 8 + j], emb[tok * 8 + j], a);
    }
    G1f[tok * 33 + g] = s * a;
  }

  // ---- stage this block's 128x24 tokens, coalesced ----
  const long gbase = (long)blockIdx.x * (128 * 24);
  #pragma unroll
  for (int k = 0; k < 12; ++k) {
    const int i = tid + k * 256;
    TK[(i / 24) * 25 + (i % 24)] = inputs[gbase + i];
  }
  __syncthreads();

  const int sl = wid * 32 + col;
  unsigned pkw[4] = {0u, 0u, 0u, 0u};
  #pragma unroll
  for (int t = 0; t < 24; ++t)
    pkw[t / 6] |= ((unsigned)TK[sl * 25 + t]) << (5 * (t % 6));
  const unsigned pk0 = pkw[0], pk1 = pkw[1], pk2_ = pkw[2], pk3 = pkw[3];

  // ---- weight A-frags (lane<32: row=col of W, k=0..7 scaled; else zero) ----
  auto loadW = [&](const float* w) -> half8 {
    H8U u;
    u.u[0] = u.u[1] = u.u[2] = u.u[3] = 0u;
    if (half_ == 0 && col < 24) {
      const float s = (col < 16) ? -LOG2E : 2.f * LOG2E;
      const float4* p = (const float4*)(w + col * 8);
      const float4 x = p[0], y = p[1];
      u.p[0] = pk2f(x.x * s, x.y * s);
      u.p[1] = pk2f(x.z * s, x.w * s);
      u.p[2] = pk2f(y.x * s, y.y * s);
      u.p[3] = pk2f(y.z * s, y.w * s);
    }
    return u.h;
  };
  const half8 wa1  = loadW(w_hh1);
  const half8 wa2i = loadW(w_ih2);
  const half8 wa2h = loadW(w_hh2);

  // ---- layer-2 bias C-frag ----
  f32x16 c2;
  #pragma unroll
  for (int r = 0; r < 16; ++r) {
    const int m = (r & 3) + 8 * (r >> 2) + 4 * half_;
    float v;
    if (m < 16)      v = -LOG2E * (b_ih2[m] + b_hh2[m]);
    else if (m < 24) v = 2.f * LOG2E * b_hh2[m];
    else             v = 0.f;
    c2[r] = v;
  }
  float bn1[4], bi2n[4];
  #pragma unroll
  for (int i = 0; i < 4; ++i) {
    bn1[i]  = 2.f * LOG2E * b_hh1[16 + 4 * half_ + i];
    bi2n[i] = 2.f * LOG2E * b_ih2[16 + 4 * half_ + i];
  }

  float h1v[4] = {0.f, 0.f, 0.f, 0.f}, h2v[4] = {0.f, 0.f, 0.f, 0.f};
  H8U f1, f2;
  f1.u[0] = f1.u[1] = f1.u[2] = f1.u[3] = 0u;
  f2 = f1;

  const float* g1base = G1f + half_ * 4;

  // ---- phase stagger: hashed blockIdx -> 0..896-cycle sleep (wave-uniform
  // scalar branches; no barrier after this point keeps waves desynced) ----
  {
    const unsigned key =
        (blockIdx.x ^ (blockIdx.x >> 3) ^ (blockIdx.x >> 6)) & 7u;
    if (key & 1u) __builtin_amdgcn_s_sleep(2);
    if (key & 2u) __builtin_amdgcn_s_sleep(4);
    if (key & 4u) __builtin_amdgcn_s_sleep(8);
  }

  // ---- prologue prefetch: G1 row for t=0 ----
  float cu[12];
  {
    const float* gp = g1base + (pk0 & 31u) * 33;
    cu[0] = gp[0];  cu[1] = gp[1];  cu[2]  = gp[2];  cu[3]  = gp[3];
    cu[4] = gp[8];  cu[5] = gp[9];  cu[6]  = gp[10]; cu[7]  = gp[11];
    cu[8] = gp[16]; cu[9] = gp[17]; cu[10] = gp[18]; cu[11] = gp[19];
  }

  // ---- rolled time loop: 4 outer iterations x 6 unrolled steps ----
  for (int t6 = 0; t6 < 4; ++t6) {
    const unsigned pw  = (t6 == 0) ? pk0 : (t6 == 1) ? pk1 : (t6 == 2) ? pk2_ : pk3;
    const unsigned pwn = (t6 == 0) ? pk1 : (t6 == 1) ? pk2_ : pk3;  // next dword (t6==3: dummy)

    #pragma unroll
    for (int j = 0; j < 6; ++j) {
      // 1. issue next step's G1-row reads (used next iteration; latency hidden
      //    under this step's MFMAs + trans chains)
      const unsigned tokn = (j < 5) ? ((pw >> (5 * (j + 1))) & 31u) : (pwn & 31u);
      const float* gq = g1base + tokn * 33;
      float nx[12];
      nx[0] = gq[0];  nx[1] = gq[1];  nx[2]  = gq[2];  nx[3]  = gq[3];
      nx[4] = gq[8];  nx[5] = gq[9];  nx[6]  = gq[10]; nx[7]  = gq[11];
      nx[8] = gq[16]; nx[9] = gq[17]; nx[10] = gq[18]; nx[11] = gq[19];

      // 2. both ready-at-top MFMAs
      const f32x16 dh = MFMA_(wa2h, f2.h, c2);     // L2 recurrent
      f32x16 c1;
      c1[0] = cu[0]; c1[1] = cu[1]; c1[2] = cu[2]; c1[3] = cu[3];
      c1[4] = cu[4]; c1[5] = cu[5]; c1[6] = cu[6]; c1[7] = cu[7];
      c1[8] = bn1[0]; c1[9] = bn1[1]; c1[10] = bn1[2]; c1[11] = bn1[3];
      c1[12] = 0.f; c1[13] = 0.f; c1[14] = 0.f; c1[15] = 0.f;
      const f32x16 d1 = MFMA_(wa1, f1.h, c1);      // L1 full gates

      // 3. layer-1 cell
      #pragma unroll
      for (int i = 0; i < 4; ++i) {
        const float r = __builtin_amdgcn_rcpf(1.f + __builtin_amdgcn_exp2f(d1[i]));
        const float z = __builtin_amdgcn_rcpf(1.f + __builtin_amdgcn_exp2f(d1[4 + i]));
        const float na = fmaf(r, d1[8 + i], cu[8 + i]);
        const float n = fmaf(-2.f, __builtin_amdgcn_rcpf(1.f + __builtin_amdgcn_exp2f(na)), 1.f);
        h1v[i] = n + z * (h1v[i] - n);
      }
      {
        const unsigned a = __builtin_bit_cast(unsigned, pk2f(h1v[0], h1v[1]));
        const unsigned b = __builtin_bit_cast(unsigned, pk2f(h1v[2], h1v[3]));
        f1.u[0] = a; f1.u[1] = b;
        f1.u[2] = from_upper(a); f1.u[3] = from_upper(b);
      }

      const f32x16 dg = MFMA_(wa2i, f1.h, dh);     // L2 input gates, chained C

      // 4. layer-2 cell
      #pragma unroll
      for (int i = 0; i < 4; ++i) {
        const float r = __builtin_amdgcn_rcpf(1.f + __builtin_amdgcn_exp2f(dg[i]));
        const float z = __builtin_amdgcn_rcpf(1.f + __builtin_amdgcn_exp2f(dg[4 + i]));
        const float gin = dg[8 + i] - dh[8 + i] + bi2n[i];
        const float na = fmaf(r, dh[8 + i], gin);
        const float n = fmaf(-2.f, __builtin_amdgcn_rcpf(1.f + __builtin_amdgcn_exp2f(na)), 1.f);
        h2v[i] = n + z * (h2v[i] - n);
      }
      {
        const unsigned a = __builtin_bit_cast(unsigned, pk2f(h2v[0], h2v[1]));
        const unsigned b = __builtin_bit_cast(unsigned, pk2f(h2v[2], h2v[3]));
        f2.u[0] = a; f2.u[1] = b;
        f2.u[2] = from_upper(a); f2.u[3] = from_upper(b);
      }

      // 5. commit prefetched row (register rename under full unroll)
      #pragma unroll
      for (int k = 0; k < 12; ++k) cu[k] = nx[k];
    }
  }

  const long seq = (long)blockIdx.x * 128 + sl;
  *(float4*)(out + seq * 8 + 4 * half_) =
      make_float4(h2v[0], h2v[1], h2v[2], h2v[3]);
}

extern "C" void kernel_launch(void* const* d_in, const int* in_sizes, int n_in,
                              void* d_out, int out_size, void* d_ws, size_t ws_size,
                              hipStream_t stream) {
  const int*   inputs = (const int*)d_in[0];
  const float* emb    = (const float*)d_in[1];
  const float* w_ih1  = (const float*)d_in[2];
  const float* w_hh1  = (const float*)d_in[3];
  const float* b_ih1  = (const float*)d_in[4];
  const float* b_hh1  = (const float*)d_in[5];
  const float* w_ih2  = (const float*)d_in[6];
  const float* w_hh2  = (const float*)d_in[7];
  const float* b_ih2  = (const float*)d_in[8];
  const float* b_hh2  = (const float*)d_in[9];
  float* out = (float*)d_out;

  const int B = in_sizes[0] / 24;        // 131072
  const int grid = B / 128;              // 1024 blocks, 4 waves/SIMD

  hipLaunchKernelGGL(gru2_mfma, dim3(grid), dim3(256), 0, stream,
                     inputs, emb, w_ih1, w_hh1, b_ih1, b_hh1,
                     w_ih2, w_hh2, b_ih2, b_hh2, out);
}